// Round 1
// baseline (385.295 us; speedup 1.0000x reference)
//
#include <hip/hip_runtime.h>
#include <hip/hip_bf16.h>

#define BATCH 4096
#define DK    2048
#define NCOMP 8
#define CCH   1024
#define NC    8192   // NCOMP*CCH

typedef unsigned int u32;
typedef unsigned short u16;
// Per cdna_hip_programming.md §3: frag type for bf16 16x16x32 MFMA
typedef short bf16x8 __attribute__((ext_vector_type(8)));
typedef float f32x4 __attribute__((ext_vector_type(4)));

__device__ __forceinline__ u16 f2bf(float f) {
    union { float f; u32 u; } v; v.f = f;
    u32 r = v.u + 0x7fffu + ((v.u >> 16) & 1u);  // RNE
    return (u16)(r >> 16);
}

// ---------------- f32 -> bf16 cast, 8 elems/thread, vectorized ----------------
__global__ void cvt_kernel(const float* __restrict__ in, u16* __restrict__ out, int n8) {
    int i = blockIdx.x * blockDim.x + threadIdx.x;
    if (i >= n8) return;
    const float4* p = (const float4*)in + (size_t)i * 2;
    float4 a = p[0], b = p[1];
    union { u16 s[8]; uint4 v; } o;
    o.s[0] = f2bf(a.x); o.s[1] = f2bf(a.y); o.s[2] = f2bf(a.z); o.s[3] = f2bf(a.w);
    o.s[4] = f2bf(b.x); o.s[5] = f2bf(b.y); o.s[6] = f2bf(b.z); o.s[7] = f2bf(b.w);
    ((uint4*)out)[i] = o.v;
}

// ---------------- gate: one wave per row; replicate reference arithmetic ----------------
__global__ void gate_kernel(const float* __restrict__ x, const float* __restrict__ wg,
                            const float* __restrict__ wgb, float* __restrict__ Gout) {
    int wid = (int)((blockIdx.x * blockDim.x + threadIdx.x) >> 6);
    int l = threadIdx.x & 63;
    if (wid >= BATCH) return;
    const float4* xr = (const float4*)(x + (size_t)wid * DK);
    const float4* wr = (const float4*)wg;
    float s = 0.f;
#pragma unroll
    for (int j = 0; j < 8; ++j) {
        float4 a = xr[j * 64 + l];
        float4 b = wr[j * 64 + l];
        s += a.x * b.x; s += a.y * b.y; s += a.z * b.z; s += a.w * b.w;
    }
#pragma unroll
    for (int off = 32; off; off >>= 1) s += __shfl_xor(s, off, 64);
    if (l == 0) {
        float g = 0.5f * (float)NCOMP * (1.0f + tanhf(s + wgb[0]));
        float k = floorf(g);
        float mh[NCOMP];
        float den = 0.f;
#pragma unroll
        for (int n = 0; n < NCOMP; ++n) {
            float m = ((float)n <= k) ? 1.0f : 0.0f;
            m = (m - g) + g;            // replicate straight-through forward rounding
            mh[n] = m;
            den += fabsf(m);            // sequential, like np.sum over 8 elems
        }
        den = fmaxf(den, 1e-12f);
#pragma unroll
        for (int n = 0; n < NCOMP; ++n) Gout[wid * NCOMP + n] = mh[n] / den;
    }
}

// ---------------- bf16 MFMA GEMM, m97 128x128 structure, fused epilogue ----------------
#define BM 128
#define BN 128
#define BKK 32

__global__ __launch_bounds__(256, 2)
void gemm_kernel(const u16* __restrict__ A,    // [4096,2048] bf16 bits
                 const u16* __restrict__ Bw,   // [8192,2048] bf16 bits (W flattened, B^T layout)
                 const float* __restrict__ bias, // [8192]
                 const float* __restrict__ Gtab, // [4096,8]
                 float* __restrict__ E) {        // [4096,8192]
    __shared__ u16 As[BM * BKK];  // 8 KiB
    __shared__ u16 Bs[BN * BKK];  // 8 KiB
    int tid = threadIdx.x;
    int w = tid >> 6, l = tid & 63;

    const int nbc = NC / BN;              // 64
    const int cpx = (BATCH / BM) * nbc / 8; // 256 (nwg=2048, %8==0 -> bijective)
    int bid = blockIdx.x;
    int swz = (bid & 7) * cpx + (bid >> 3);
    int brow = (swz / nbc) * BM;
    int bcol = (swz % nbc) * BN;
    int wr = w >> 1, wc = w & 1;

    f32x4 acc[4][4] = {};

    // staging: 512 chunks of 16B per tile; thread t covers chunks t and t+256
    int r0 = tid >> 2, kp0 = (tid & 3) * 8;   // chunk c -> row c>>2, k (c&3)*8
    u16* ldsA0 = As + (size_t)(w * 64) * 8;          // wave-uniform dests
    u16* ldsA1 = As + (size_t)(256 + w * 64) * 8;
    u16* ldsB0 = Bs + (size_t)(w * 64) * 8;
    u16* ldsB1 = Bs + (size_t)(256 + w * 64) * 8;
    const u16* gA0 = A + (size_t)(brow + r0) * DK + kp0;
    const u16* gA1 = A + (size_t)(brow + r0 + 64) * DK + kp0;
    const u16* gB0 = Bw + (size_t)(bcol + r0) * DK + kp0;
    const u16* gB1 = Bw + (size_t)(bcol + r0 + 64) * DK + kp0;

    int arow = l & 15;
    int kgrp = (l >> 4) * 8;

    for (int k0 = 0; k0 < DK; k0 += BKK) {
        __builtin_amdgcn_global_load_lds((const __attribute__((address_space(1))) u32*)(gA0 + k0),
                                         (__attribute__((address_space(3))) u32*)ldsA0, 16, 0, 0);
        __builtin_amdgcn_global_load_lds((const __attribute__((address_space(1))) u32*)(gA1 + k0),
                                         (__attribute__((address_space(3))) u32*)ldsA1, 16, 0, 0);
        __builtin_amdgcn_global_load_lds((const __attribute__((address_space(1))) u32*)(gB0 + k0),
                                         (__attribute__((address_space(3))) u32*)ldsB0, 16, 0, 0);
        __builtin_amdgcn_global_load_lds((const __attribute__((address_space(1))) u32*)(gB1 + k0),
                                         (__attribute__((address_space(3))) u32*)ldsB1, 16, 0, 0);
        __syncthreads();  // compiler emits vmcnt(0) drain -> LDS valid

        bf16x8 af[4], bf[4];
#pragma unroll
        for (int mi = 0; mi < 4; ++mi)
            af[mi] = *(const bf16x8*)&As[(wr * 64 + mi * 16 + arow) * BKK + kgrp];
#pragma unroll
        for (int ni = 0; ni < 4; ++ni)
            bf[ni] = *(const bf16x8*)&Bs[(wc * 64 + ni * 16 + arow) * BKK + kgrp];
#pragma unroll
        for (int mi = 0; mi < 4; ++mi)
#pragma unroll
            for (int ni = 0; ni < 4; ++ni)
                acc[mi][ni] = __builtin_amdgcn_mfma_f32_16x16x32_bf16(af[mi], bf[ni], acc[mi][ni], 0, 0, 0);
        __syncthreads();  // all reads done before next stage overwrites
    }

    // epilogue: E = G[row, n] * (acc + bias[col]); n uniform per block (128 | 1024)
    int n = bcol >> 10;
    int rbase = brow + wr * 64;
    int cbase = bcol + wc * 64;
#pragma unroll
    for (int mi = 0; mi < 4; ++mi) {
#pragma unroll
        for (int r = 0; r < 4; ++r) {
            int row = rbase + mi * 16 + (l >> 4) * 4 + r;
            float gv = Gtab[row * NCOMP + n];
#pragma unroll
            for (int ni = 0; ni < 4; ++ni) {
                int col = cbase + ni * 16 + (l & 15);
                E[(size_t)row * NC + col] = gv * (acc[mi][ni][r] + bias[col]);
            }
        }
    }
}

extern "C" void kernel_launch(void* const* d_in, const int* in_sizes, int n_in,
                              void* d_out, int out_size, void* d_ws, size_t ws_size,
                              hipStream_t stream) {
    const float* x   = (const float*)d_in[0];
    const float* W   = (const float*)d_in[1];
    const float* b   = (const float*)d_in[2];
    const float* wgw = (const float*)d_in[3];
    const float* wgb = (const float*)d_in[4];
    float* E = (float*)d_out;
    float* G = E + (size_t)BATCH * NC;   // outputs concatenated: E then G

    u16* xb = (u16*)d_ws;                      // 4096*2048 bf16 = 16 MiB
    u16* Wb = xb + (size_t)BATCH * DK;         // 8192*2048 bf16 = 32 MiB

    int nx8 = BATCH * DK / 8;
    cvt_kernel<<<nx8 / 256, 256, 0, stream>>>(x, xb, nx8);
    int nw8 = NC * DK / 8;
    cvt_kernel<<<nw8 / 256, 256, 0, stream>>>(W, Wb, nw8);
    gate_kernel<<<BATCH / 4, 256, 0, stream>>>(x, wgw, wgb, G);
    gemm_kernel<<<(BATCH / BM) * (NC / BN), 256, 0, stream>>>(xb, Wb, b, G, E);
}

// Round 2
// 327.949 us; speedup vs baseline: 1.1749x; 1.1749x over previous
//
#include <hip/hip_runtime.h>
#include <hip/hip_bf16.h>

#define BATCH 4096
#define DK    2048
#define NCOMP 8
#define NC    8192
#define NT    (DK / 64)

typedef unsigned int u32;
typedef unsigned short u16;
typedef short bf16x8 __attribute__((ext_vector_type(8)));
typedef float f32x4 __attribute__((ext_vector_type(4)));

__device__ __forceinline__ u16 f2bf(float f) {
    union { float f; u32 u; } v; v.f = f;
    u32 r = v.u + 0x7fffu + ((v.u >> 16) & 1u);  // RNE
    return (u16)(r >> 16);
}

// ---------------- W cast: one float4 -> ushort4 per thread, fully coalesced ----------------
__global__ void cvtW_kernel(const float* __restrict__ in, u16* __restrict__ out) {
    int i = blockIdx.x * blockDim.x + threadIdx.x;
    float4 a = ((const float4*)in)[i];
    ushort4 o = { f2bf(a.x), f2bf(a.y), f2bf(a.z), f2bf(a.w) };
    ((ushort4*)out)[i] = o;
}

// ---------------- fused x cast + gate: one block per row, x read ONCE ----------------
__global__ __launch_bounds__(256)
void xgate_kernel(const float* __restrict__ x, const float* __restrict__ wg,
                  const float* __restrict__ wgb, u16* __restrict__ xb,
                  float* __restrict__ G) {
    int row = blockIdx.x;
    int t = threadIdx.x;
    const float4* xr = (const float4*)(x + (size_t)row * DK);
    const float4* wr = (const float4*)wg;
    float4 a = xr[t], b = xr[t + 256];
    float4 wa = wr[t], wb = wr[t + 256];
    float s = a.x*wa.x + a.y*wa.y + a.z*wa.z + a.w*wa.w
            + b.x*wb.x + b.y*wb.y + b.z*wb.z + b.w*wb.w;
    ushort4 o1 = { f2bf(a.x), f2bf(a.y), f2bf(a.z), f2bf(a.w) };
    ushort4 o2 = { f2bf(b.x), f2bf(b.y), f2bf(b.z), f2bf(b.w) };
    ushort4* xo = (ushort4*)(xb + (size_t)row * DK);
    xo[t] = o1;
    xo[t + 256] = o2;
    __shared__ float red[4];
#pragma unroll
    for (int off = 32; off; off >>= 1) s += __shfl_xor(s, off, 64);
    if ((t & 63) == 0) red[t >> 6] = s;
    __syncthreads();
    if (t == 0) {
        float sum = (red[0] + red[1]) + (red[2] + red[3]);
        float g = 0.5f * (float)NCOMP * (1.0f + tanhf(sum + wgb[0]));
        float k = floorf(g);
        float mh[NCOMP]; float den = 0.f;
#pragma unroll
        for (int n = 0; n < NCOMP; ++n) {
            float m = ((float)n <= k) ? 1.0f : 0.0f;
            m = (m - g) + g;            // replicate straight-through forward rounding
            mh[n] = m; den += fabsf(m);
        }
        den = fmaxf(den, 1e-12f);
#pragma unroll
        for (int n = 0; n < NCOMP; ++n) G[(size_t)row * NCOMP + n] = mh[n] / den;
    }
}

// ---------------- 256x256 8-phase bf16 MFMA GEMM (T1+T2+T3+T5), fused epilogue ----------------
// LDS half-tile layout: [128 rows][8 slots of 16B]; content at (row, slot) is
// global (row, slot ^ (row&7))  -> read with the same XOR (involution, rule #21).
__device__ __forceinline__ void stage_half(const u16* __restrict__ gbase,
                                           u16* __restrict__ ldsHalf, int tid) {
#pragma unroll
    for (int i = 0; i < 2; ++i) {
        int c = tid + i * 512;                 // chunk in [0,1024)
        int row = c >> 3;
        int slot = (c & 7) ^ (row & 7);        // pre-swizzled GLOBAL source slot
        const u16* src = gbase + (size_t)row * DK + slot * 8;
        u16* dst = ldsHalf + (size_t)(c >> 6) * 512;   // wave-uniform base, lane*16 added by HW
        __builtin_amdgcn_global_load_lds((const __attribute__((address_space(1))) u32*)src,
                                         (__attribute__((address_space(3))) u32*)dst, 16, 0, 0);
    }
}

__device__ __forceinline__ bf16x8 frag(const u16* __restrict__ h, int lrow, int slot) {
    return *(const bf16x8*)(h + lrow * 64 + ((slot ^ (lrow & 7)) << 3));
}

#define PH_MID()  do { __builtin_amdgcn_s_barrier(); \
    asm volatile("s_waitcnt lgkmcnt(0)" ::: "memory"); \
    __builtin_amdgcn_sched_barrier(0); \
    __builtin_amdgcn_s_setprio(1); } while (0)
#define PH_END()  do { __builtin_amdgcn_s_setprio(0); \
    __builtin_amdgcn_s_barrier(); } while (0)

__global__ __launch_bounds__(512, 2)
void gemm_kernel(const u16* __restrict__ A, const u16* __restrict__ Bw,
                 const float* __restrict__ bias, const float* __restrict__ Gtab,
                 float* __restrict__ E) {
    __shared__ u16 lds[2][2][2][128 * 64];   // [buf][A/B][half][16KB] = 128 KiB
    int tid = threadIdx.x;
    int l = tid & 63;
    int w = tid >> 6;
    int wr = w >> 2, wc = w & 3;             // 2 x 4 waves
    int r16 = l & 15, kg = l >> 4;

    int bid = blockIdx.x;
    int swz = (bid & 7) * 64 + (bid >> 3);   // 512 blocks, bijective XCD swizzle
    int brow = (swz >> 5) * 256;
    int bcol = (swz & 31) * 256;

    f32x4 acc[8][4] = {};

    const u16* gA = A + (size_t)brow * DK;
    const u16* gB = Bw + (size_t)bcol * DK;

    // prologue: stage tile 0 into buf 0
    stage_half(gA,              lds[0][0][0], tid);
    stage_half(gA + 128 * DK,   lds[0][0][1], tid);
    stage_half(gB,              lds[0][1][0], tid);
    stage_half(gB + 128 * DK,   lds[0][1][1], tid);
    asm volatile("s_waitcnt vmcnt(0)" ::: "memory");
    __builtin_amdgcn_s_barrier();

    for (int t = 0; t < NT; ++t) {
        int buf = t & 1, nb = buf ^ 1;
        const u16* Ah = lds[buf][0][wr];
        const u16* Bh = lds[buf][1][wc >> 1];
        int brB = (wc & 1) * 64;
        int koff = (t + 1) * 64;
        bool pf = (t + 1) < NT;

        bf16x8 aF[4][2], bF[2][2];
        // ---- phase 1: quadrant (mh0,nh0); stage next A halves
#pragma unroll
        for (int j = 0; j < 4; ++j)
#pragma unroll
            for (int kk = 0; kk < 2; ++kk)
                aF[j][kk] = frag(Ah, j * 16 + r16, kk * 4 + kg);
#pragma unroll
        for (int jn = 0; jn < 2; ++jn)
#pragma unroll
            for (int kk = 0; kk < 2; ++kk)
                bF[jn][kk] = frag(Bh, brB + jn * 16 + r16, kk * 4 + kg);
        if (pf) {
            stage_half(gA + koff,            lds[nb][0][0], tid);
            stage_half(gA + 128 * DK + koff, lds[nb][0][1], tid);
        }
        PH_MID();
#pragma unroll
        for (int j = 0; j < 4; ++j)
#pragma unroll
            for (int jn = 0; jn < 2; ++jn)
#pragma unroll
                for (int kk = 0; kk < 2; ++kk)
                    acc[j][jn] = __builtin_amdgcn_mfma_f32_16x16x32_bf16(aF[j][kk], bF[jn][kk], acc[j][jn], 0, 0, 0);
        PH_END();

        // ---- phase 2: quadrant (mh0,nh1); stage next B halves; reuse aF
        bf16x8 bG[2][2];
#pragma unroll
        for (int jn = 0; jn < 2; ++jn)
#pragma unroll
            for (int kk = 0; kk < 2; ++kk)
                bG[jn][kk] = frag(Bh, brB + 32 + jn * 16 + r16, kk * 4 + kg);
        if (pf) {
            stage_half(gB + koff,            lds[nb][1][0], tid);
            stage_half(gB + 128 * DK + koff, lds[nb][1][1], tid);
        }
        PH_MID();
#pragma unroll
        for (int j = 0; j < 4; ++j)
#pragma unroll
            for (int jn = 0; jn < 2; ++jn)
#pragma unroll
                for (int kk = 0; kk < 2; ++kk)
                    acc[j][2 + jn] = __builtin_amdgcn_mfma_f32_16x16x32_bf16(aF[j][kk], bG[jn][kk], acc[j][2 + jn], 0, 0, 0);
        PH_END();

        // ---- phase 3: quadrant (mh1,nh1); reuse bG
        bf16x8 aG[4][2];
#pragma unroll
        for (int j = 0; j < 4; ++j)
#pragma unroll
            for (int kk = 0; kk < 2; ++kk)
                aG[j][kk] = frag(Ah, 64 + j * 16 + r16, kk * 4 + kg);
        PH_MID();
#pragma unroll
        for (int j = 0; j < 4; ++j)
#pragma unroll
            for (int jn = 0; jn < 2; ++jn)
#pragma unroll
                for (int kk = 0; kk < 2; ++kk)
                    acc[4 + j][2 + jn] = __builtin_amdgcn_mfma_f32_16x16x32_bf16(aG[j][kk], bG[jn][kk], acc[4 + j][2 + jn], 0, 0, 0);
        PH_END();

        // ---- phase 4: quadrant (mh1,nh0); re-read B(nh0); reuse aG
#pragma unroll
        for (int jn = 0; jn < 2; ++jn)
#pragma unroll
            for (int kk = 0; kk < 2; ++kk)
                bF[jn][kk] = frag(Bh, brB + jn * 16 + r16, kk * 4 + kg);
        PH_MID();
#pragma unroll
        for (int j = 0; j < 4; ++j)
#pragma unroll
            for (int jn = 0; jn < 2; ++jn)
#pragma unroll
                for (int kk = 0; kk < 2; ++kk)
                    acc[4 + j][jn] = __builtin_amdgcn_mfma_f32_16x16x32_bf16(aG[j][kk], bF[jn][kk], acc[4 + j][jn], 0, 0, 0);
        __builtin_amdgcn_s_setprio(0);
        if (pf) asm volatile("s_waitcnt vmcnt(0)" ::: "memory");  // next tile fully staged
        __builtin_amdgcn_s_barrier();
    }

    // epilogue: E = G[row, n] * (acc + bias[col]); n uniform per wave (cbase 64-aligned in 1024)
    int ncomp = (bcol + wc * 64) >> 10;
    int rbase = brow + wr * 128;
    int cbase = bcol + wc * 64;
    float bs[4];
#pragma unroll
    for (int ni = 0; ni < 4; ++ni) bs[ni] = bias[cbase + ni * 16 + r16];
#pragma unroll
    for (int mi = 0; mi < 8; ++mi)
#pragma unroll
        for (int r = 0; r < 4; ++r) {
            int row = rbase + mi * 16 + kg * 4 + r;
            float gv = Gtab[(size_t)row * NCOMP + ncomp];
            float* Erow = E + (size_t)row * NC + cbase;
#pragma unroll
            for (int ni = 0; ni < 4; ++ni)
                Erow[ni * 16 + r16] = gv * (acc[mi][ni][r] + bs[ni]);
        }
}

extern "C" void kernel_launch(void* const* d_in, const int* in_sizes, int n_in,
                              void* d_out, int out_size, void* d_ws, size_t ws_size,
                              hipStream_t stream) {
    const float* x   = (const float*)d_in[0];
    const float* W   = (const float*)d_in[1];
    const float* b   = (const float*)d_in[2];
    const float* wgw = (const float*)d_in[3];
    const float* wgb = (const float*)d_in[4];
    float* E = (float*)d_out;
    float* G = E + (size_t)BATCH * NC;

    u16* xb = (u16*)d_ws;                      // 16 MiB
    u16* Wb = xb + (size_t)BATCH * DK;         // 32 MiB

    cvtW_kernel<<<NC * DK / 4 / 256, 256, 0, stream>>>(W, Wb);
    xgate_kernel<<<BATCH, 256, 0, stream>>>(x, wgw, wgb, xb, G);
    gemm_kernel<<<(BATCH / 256) * (NC / 256), 512, 0, stream>>>(xb, Wb, b, G, E);
}

// Round 3
// 326.805 us; speedup vs baseline: 1.1790x; 1.0035x over previous
//
#include <hip/hip_runtime.h>
#include <hip/hip_bf16.h>

#define BATCH 4096
#define DK    2048
#define NCOMP 8
#define NC    8192
#define NT    (DK / 64)

typedef unsigned int u32;
typedef unsigned short u16;
typedef short bf16x8 __attribute__((ext_vector_type(8)));
typedef float f32x4 __attribute__((ext_vector_type(4)));

__device__ __forceinline__ u16 f2bf(float f) {
    union { float f; u32 u; } v; v.f = f;
    u32 r = v.u + 0x7fffu + ((v.u >> 16) & 1u);  // RNE
    return (u16)(r >> 16);
}

// ---------------- W cast: one float4 -> ushort4 per thread, fully coalesced ----------------
__global__ void cvtW_kernel(const float* __restrict__ in, u16* __restrict__ out) {
    int i = blockIdx.x * blockDim.x + threadIdx.x;
    float4 a = ((const float4*)in)[i];
    ushort4 o = { f2bf(a.x), f2bf(a.y), f2bf(a.z), f2bf(a.w) };
    ((ushort4*)out)[i] = o;
}

// ---------------- fused x cast + gate: one block per row, x read ONCE ----------------
__global__ __launch_bounds__(256)
void xgate_kernel(const float* __restrict__ x, const float* __restrict__ wg,
                  const float* __restrict__ wgb, u16* __restrict__ xb,
                  float* __restrict__ G) {
    int row = blockIdx.x;
    int t = threadIdx.x;
    const float4* xr = (const float4*)(x + (size_t)row * DK);
    const float4* wr = (const float4*)wg;
    float4 a = xr[t], b = xr[t + 256];
    float4 wa = wr[t], wb = wr[t + 256];
    float s = a.x*wa.x + a.y*wa.y + a.z*wa.z + a.w*wa.w
            + b.x*wb.x + b.y*wb.y + b.z*wb.z + b.w*wb.w;
    ushort4 o1 = { f2bf(a.x), f2bf(a.y), f2bf(a.z), f2bf(a.w) };
    ushort4 o2 = { f2bf(b.x), f2bf(b.y), f2bf(b.z), f2bf(b.w) };
    ushort4* xo = (ushort4*)(xb + (size_t)row * DK);
    xo[t] = o1;
    xo[t + 256] = o2;
    __shared__ float red[4];
#pragma unroll
    for (int off = 32; off; off >>= 1) s += __shfl_xor(s, off, 64);
    if ((t & 63) == 0) red[t >> 6] = s;
    __syncthreads();
    if (t == 0) {
        float sum = (red[0] + red[1]) + (red[2] + red[3]);
        float g = 0.5f * (float)NCOMP * (1.0f + tanhf(sum + wgb[0]));
        float k = floorf(g);
        float mh[NCOMP]; float den = 0.f;
#pragma unroll
        for (int n = 0; n < NCOMP; ++n) {
            float m = ((float)n <= k) ? 1.0f : 0.0f;
            m = (m - g) + g;            // replicate straight-through forward rounding
            mh[n] = m; den += fabsf(m);
        }
        den = fmaxf(den, 1e-12f);
#pragma unroll
        for (int n = 0; n < NCOMP; ++n) G[(size_t)row * NCOMP + n] = mh[n] / den;
    }
}

// ---------------- 256x256 bf16 MFMA GEMM, counted-vmcnt 4-phase schedule ----------------
// LDS half-tile layout: [128 rows][8 slots of 16B]; content at (row, slot) is
// global (row, slot ^ (row&7))  -> read with the same XOR (involution, rule #21).
__device__ __forceinline__ void stage_half(const u16* __restrict__ gbase,
                                           u16* __restrict__ ldsHalf, int tid) {
#pragma unroll
    for (int i = 0; i < 2; ++i) {
        int c = tid + i * 512;                 // chunk in [0,1024)
        int row = c >> 3;
        int slot = (c & 7) ^ (row & 7);        // pre-swizzled GLOBAL source slot
        const u16* src = gbase + (size_t)row * DK + slot * 8;
        u16* dst = ldsHalf + (size_t)(c >> 6) * 512;   // wave-uniform base, lane*16 added by HW
        __builtin_amdgcn_global_load_lds((const __attribute__((address_space(1))) u32*)src,
                                         (__attribute__((address_space(3))) u32*)dst, 16, 0, 0);
    }
}

__device__ __forceinline__ bf16x8 frag(const u16* __restrict__ h, int lrow, int slot) {
    return *(const bf16x8*)(h + lrow * 64 + ((slot ^ (lrow & 7)) << 3));
}

#define PH_MID()  do { __builtin_amdgcn_s_barrier(); \
    asm volatile("s_waitcnt lgkmcnt(0)" ::: "memory"); \
    __builtin_amdgcn_sched_barrier(0); \
    __builtin_amdgcn_s_setprio(1); } while (0)
#define PH_END()  do { __builtin_amdgcn_s_setprio(0); \
    __builtin_amdgcn_s_barrier(); } while (0)

__global__ __launch_bounds__(512, 2)
void gemm_kernel(const u16* __restrict__ A, const u16* __restrict__ Bw,
                 const float* __restrict__ bias, const float* __restrict__ Gtab,
                 float* __restrict__ E) {
    __shared__ u16 lds[2][2][2][128 * 64];   // [buf][A/B][half][16KB] = 128 KiB
    int tid = threadIdx.x;
    int l = tid & 63;
    int w = tid >> 6;
    int wr = w >> 2, wc = w & 3;             // 2 x 4 waves
    int r16 = l & 15, kg = l >> 4;

    int bid = blockIdx.x;
    int swz = (bid & 7) * 64 + (bid >> 3);   // 512 blocks, bijective XCD swizzle
    int brow = (swz >> 5) * 256;
    int bcol = (swz & 31) * 256;

    f32x4 acc[8][4] = {};

    const u16* gA = A + (size_t)brow * DK;
    const u16* gB = Bw + (size_t)bcol * DK;

    // prologue: t0 fully, then t1.{B0,B1,A0}; t1.A1 comes from t0's phase 1
    stage_half(gA,                 lds[0][0][0], tid);
    stage_half(gA + 128 * DK,      lds[0][0][1], tid);
    stage_half(gB,                 lds[0][1][0], tid);
    stage_half(gB + 128 * DK,      lds[0][1][1], tid);
    stage_half(gB + 64,            lds[1][1][0], tid);
    stage_half(gB + 128 * DK + 64, lds[1][1][1], tid);
    stage_half(gA + 64,            lds[1][0][0], tid);
    asm volatile("s_waitcnt vmcnt(6)" ::: "memory");   // t0's 8 loads retired
    __builtin_amdgcn_s_barrier();

    for (int t = 0; t < NT; ++t) {
        int p = t & 1;
        const u16* Ah = lds[p][0][wr];
        const u16* Bh = lds[p][1][wc >> 1];
        int brB = (wc & 1) * 64;
        bool pf1 = (t + 1) < NT;
        bool pf2 = (t + 2) < NT;
        int koff1 = (t + 1) * 64;
        int koff2 = (t + 2) * 64;

        bf16x8 aF[4][2], aG[4][2], bF[2][2], bG[2][2];

        // ---- phase 1: q(0,0); stage t+1.A1 -> other buf
#pragma unroll
        for (int j = 0; j < 4; ++j)
#pragma unroll
            for (int kk = 0; kk < 2; ++kk)
                aF[j][kk] = frag(Ah, j * 16 + r16, kk * 4 + kg);
#pragma unroll
        for (int jn = 0; jn < 2; ++jn)
#pragma unroll
            for (int kk = 0; kk < 2; ++kk)
                bF[jn][kk] = frag(Bh, brB + jn * 16 + r16, kk * 4 + kg);
        if (pf1) stage_half(gA + 128 * DK + koff1, lds[p ^ 1][0][1], tid);
        PH_MID();
#pragma unroll
        for (int j = 0; j < 4; ++j)
#pragma unroll
            for (int jn = 0; jn < 2; ++jn)
#pragma unroll
                for (int kk = 0; kk < 2; ++kk)
                    acc[j][jn] = __builtin_amdgcn_mfma_f32_16x16x32_bf16(aF[j][kk], bF[jn][kk], acc[j][jn], 0, 0, 0);
        PH_END();

        // ---- phase 2: q(0,1); no stage
#pragma unroll
        for (int jn = 0; jn < 2; ++jn)
#pragma unroll
            for (int kk = 0; kk < 2; ++kk)
                bG[jn][kk] = frag(Bh, brB + 32 + jn * 16 + r16, kk * 4 + kg);
        PH_MID();
#pragma unroll
        for (int j = 0; j < 4; ++j)
#pragma unroll
            for (int jn = 0; jn < 2; ++jn)
#pragma unroll
                for (int kk = 0; kk < 2; ++kk)
                    acc[j][2 + jn] = __builtin_amdgcn_mfma_f32_16x16x32_bf16(aF[j][kk], bG[jn][kk], acc[j][2 + jn], 0, 0, 0);
        PH_END();

        // ---- phase 3: q(1,1); stage t+2.B0 -> current buf (B reads done after ph2)
#pragma unroll
        for (int j = 0; j < 4; ++j)
#pragma unroll
            for (int kk = 0; kk < 2; ++kk)
                aG[j][kk] = frag(Ah, 64 + j * 16 + r16, kk * 4 + kg);
        if (pf2) stage_half(gB + koff2, lds[p][1][0], tid);
        PH_MID();
#pragma unroll
        for (int j = 0; j < 4; ++j)
#pragma unroll
            for (int jn = 0; jn < 2; ++jn)
#pragma unroll
                for (int kk = 0; kk < 2; ++kk)
                    acc[4 + j][2 + jn] = __builtin_amdgcn_mfma_f32_16x16x32_bf16(aG[j][kk], bG[jn][kk], acc[4 + j][2 + jn], 0, 0, 0);
        PH_END();

        // ---- phase 4: q(1,0) (bF held in regs); stage t+2.{B1,A0} -> current buf
        if (pf2) {
            stage_half(gB + 128 * DK + koff2, lds[p][1][1], tid);
            stage_half(gA + koff2,            lds[p][0][0], tid);
        }
        PH_MID();
#pragma unroll
        for (int j = 0; j < 4; ++j)
#pragma unroll
            for (int jn = 0; jn < 2; ++jn)
#pragma unroll
                for (int kk = 0; kk < 2; ++kk)
                    acc[4 + j][jn] = __builtin_amdgcn_mfma_f32_16x16x32_bf16(aG[j][kk], bF[jn][kk], acc[4 + j][jn], 0, 0, 0);
        __builtin_amdgcn_s_setprio(0);
        // counted vmcnt: retire through t+1.A1 (3 half-tiles x 2 loads stay in flight)
        if (pf2)      asm volatile("s_waitcnt vmcnt(6)" ::: "memory");
        else if (pf1) asm volatile("s_waitcnt vmcnt(0)" ::: "memory");
        if (pf1) __builtin_amdgcn_s_barrier();
    }

    // epilogue: E = G[row, n] * (acc + bias[col]); n uniform per wave (cbase 64-aligned in 1024)
    int ncomp = (bcol + wc * 64) >> 10;
    int rbase = brow + wr * 128;
    int cbase = bcol + wc * 64;
    float bs[4];
#pragma unroll
    for (int ni = 0; ni < 4; ++ni) bs[ni] = bias[cbase + ni * 16 + r16];
#pragma unroll
    for (int mi = 0; mi < 8; ++mi)
#pragma unroll
        for (int r = 0; r < 4; ++r) {
            int row = rbase + mi * 16 + kg * 4 + r;
            float gv = Gtab[(size_t)row * NCOMP + ncomp];
            float* Erow = E + (size_t)row * NC + cbase;
#pragma unroll
            for (int ni = 0; ni < 4; ++ni)
                Erow[ni * 16 + r16] = gv * (acc[mi][ni][r] + bs[ni]);
        }
}

extern "C" void kernel_launch(void* const* d_in, const int* in_sizes, int n_in,
                              void* d_out, int out_size, void* d_ws, size_t ws_size,
                              hipStream_t stream) {
    const float* x   = (const float*)d_in[0];
    const float* W   = (const float*)d_in[1];
    const float* b   = (const float*)d_in[2];
    const float* wgw = (const float*)d_in[3];
    const float* wgb = (const float*)d_in[4];
    float* E = (float*)d_out;
    float* G = E + (size_t)BATCH * NC;

    u16* xb = (u16*)d_ws;                      // 16 MiB
    u16* Wb = xb + (size_t)BATCH * DK;         // 32 MiB

    cvtW_kernel<<<NC * DK / 4 / 256, 256, 0, stream>>>(W, Wb);
    xgate_kernel<<<BATCH, 256, 0, stream>>>(x, wgw, wgb, xb, G);
    gemm_kernel<<<(BATCH / 256) * (NC / 256), 512, 0, stream>>>(xb, Wb, b, G, E);
}